// Round 8
// baseline (59.235 us; speedup 1.0000x reference)
//
#include <hip/hip_runtime.h>

#define NBLOCKS 2048
#define NTHREADS 256
#define FEPS 1e-7f

__device__ __forceinline__ float frcp(float x) { return __builtin_amdgcn_rcpf(x); }
// nested triples -> v_min3_f32 / v_max3_f32 selection
__device__ __forceinline__ float fmin3(float a, float b, float c) { return fminf(fminf(a, b), c); }
__device__ __forceinline__ float fmax3(float a, float b, float c) { return fmaxf(fmaxf(a, b), c); }

struct Quad {
    float px[4], py[4];   // oriented pred  (dead after clip1 -> regs freed)
    float tx[4], ty[4];   // oriented target (edges for clips 2..4)
    float area_p, area_t; // |signed quad areas|
    float d2c2;           // center-dist^2 / enclosing-box-diag^2 (order-invariant)
};

__device__ __forceinline__ void setup(Quad& q,
                                      float4 pa, float4 pb, float4 ta, float4 tb) {
    q.px[0] = pa.x; q.py[0] = pa.y; q.px[1] = pa.z; q.py[1] = pa.w;
    q.px[2] = pb.x; q.py[2] = pb.y; q.px[3] = pb.z; q.py[3] = pb.w;
    q.tx[0] = ta.x; q.ty[0] = ta.y; q.tx[1] = ta.z; q.ty[1] = ta.w;
    q.tx[2] = tb.x; q.ty[2] = tb.y; q.tx[3] = tb.z; q.ty[3] = tb.w;

    // quad shoelace, determinant identity: 2A = (x0-x2)(y1-y3) - (x1-x3)(y0-y2)
    // (algebraically identical to the reference sum; rounding differs only for
    //  |A| ~ ulp, where the orientation choice doesn't matter numerically)
    float sp = 0.5f * ((q.px[0] - q.px[2]) * (q.py[1] - q.py[3]) -
                       (q.px[1] - q.px[3]) * (q.py[0] - q.py[2]));
    float st = 0.5f * ((q.tx[0] - q.tx[2]) * (q.ty[1] - q.ty[3]) -
                       (q.tx[1] - q.tx[3]) * (q.ty[0] - q.ty[2]));

    if (sp < 0.0f) {  // reverse -> CCW
        float w;
        w = q.px[0]; q.px[0] = q.px[3]; q.px[3] = w;
        w = q.px[1]; q.px[1] = q.px[2]; q.px[2] = w;
        w = q.py[0]; q.py[0] = q.py[3]; q.py[3] = w;
        w = q.py[1]; q.py[1] = q.py[2]; q.py[2] = w;
    }
    if (st < 0.0f) {
        float w;
        w = q.tx[0]; q.tx[0] = q.tx[3]; q.tx[3] = w;
        w = q.tx[1]; q.tx[1] = q.tx[2]; q.tx[2] = w;
        w = q.ty[0]; q.ty[0] = q.ty[3]; q.ty[3] = w;
        w = q.ty[1]; q.ty[1] = q.ty[2]; q.ty[2] = w;
    }
    q.area_p = fabsf(sp);
    q.area_t = fabsf(st);

    // centers + enclosing box (invariant to vertex order -> hoisted pre-clip)
    float cpx = 0.25f * (q.px[0] + q.px[1] + q.px[2] + q.px[3]);
    float cpy = 0.25f * (q.py[0] + q.py[1] + q.py[2] + q.py[3]);
    float ctx = 0.25f * (q.tx[0] + q.tx[1] + q.tx[2] + q.tx[3]);
    float cty = 0.25f * (q.ty[0] + q.ty[1] + q.ty[2] + q.ty[3]);
    float dx = cpx - ctx, dy = cpy - cty;
    float d2 = dx * dx + dy * dy;

    float minx = fmin3(fmin3(q.px[0], q.px[1], q.px[2]),
                       fmin3(q.px[3], q.tx[0], q.tx[1]),
                       fminf(q.tx[2], q.tx[3]));
    float maxx = fmax3(fmax3(q.px[0], q.px[1], q.px[2]),
                       fmax3(q.px[3], q.tx[0], q.tx[1]),
                       fmaxf(q.tx[2], q.tx[3]));
    float miny = fmin3(fmin3(q.py[0], q.py[1], q.py[2]),
                       fmin3(q.py[3], q.ty[0], q.ty[1]),
                       fminf(q.ty[2], q.ty[3]));
    float maxy = fmax3(fmax3(q.py[0], q.py[1], q.py[2]),
                       fmax3(q.py[3], q.ty[0], q.ty[1]),
                       fmaxf(q.ty[2], q.ty[3]));
    float bx = maxx - minx, by = maxy - miny;
    float c2 = bx * bx + by * by + FEPS;
    q.d2c2 = d2 * frcp(c2);
}

// ---------------------------------------------------------------------------
// Clip 1: input polygon is exactly the 4 oriented pred vertices (n==4);
// reference iterations 4..7 are provably no-ops. Appends scatter into LDS
// (slot = m, clamp elided since m<=7 always; slot 8 = trash when the append
// predicate is false). base[s*NTHREADS] is this thread's slot s.
// c[j] = ex*vy[j] - ey*vx[j] - h, h = ex*Ay - ey*Ax (reference cross,
// re-associated; sign semantics preserved).
// ---------------------------------------------------------------------------
__device__ __forceinline__ int clip1_to_lds(float2* base, const Quad& q) {
    float ex = q.tx[1] - q.tx[0], ey = q.ty[1] - q.ty[0];
    float h = fmaf(ex, q.ty[0], -ey * q.tx[0]);
    float c[4];
#pragma unroll
    for (int j = 0; j < 4; ++j)
        c[j] = fmaf(ex, q.py[j], -fmaf(ey, q.px[j], h));
    int m = 0;
#pragma unroll
    for (int i = 0; i < 4; ++i) {
        const int ip1 = (i + 1) & 3;  // mod(i+1, n=4)
        float dc = c[i], dn = c[ip1];
        float denom = dc - dn;
        float d = (fabsf(denom) < FEPS) ? 1.0f : denom;
        float t = dc * frcp(d);
        float ipx = fmaf(t, q.px[ip1] - q.px[i], q.px[i]);
        float ipy = fmaf(t, q.py[ip1] - q.py[i], q.py[i]);
        bool sc = dc >= 0.0f, sn = dn >= 0.0f;

        int i1 = sc ? m : 8;          // m <= 2i <= 6: no clamp
        base[i1 * NTHREADS] = make_float2(q.px[i], q.py[i]);
        m += sc;

        bool aip = (sc != sn);
        int i2 = aip ? m : 8;         // m <= 7: no clamp
        base[i2 * NTHREADS] = make_float2(ipx, ipy);
        m += aip;
    }
    return m;
}

// ---------------------------------------------------------------------------
// Clips 2..4 (K = 1,2,3: target edge t[K] -> t[(K+1)&3]): read all 8 slots to
// registers up front (static indices), scatter appends back. Reference
// semantics kept exactly: valid = i<n, wrap = (i+1==n), OOB gather clamps to
// slot 7, idx = min(m,7) (elided where m<=2i proves it a no-op). No early
// exit: P(all 64 lanes done) ~ 4%, the branch cost outweighs it, and
// straight-line code lets the scheduler interleave the A/B quad streams.
// ---------------------------------------------------------------------------
template <int K>
__device__ __forceinline__ int clip_pass(float2* base, int n, const Quad& q) {
    constexpr int K1 = (K + 1) & 3;
    float ex = q.tx[K1] - q.tx[K], ey = q.ty[K1] - q.ty[K];
    float h = fmaf(ex, q.ty[K], -ey * q.tx[K]);

    float vx[8], vy[8], c[8];
#pragma unroll
    for (int j = 0; j < 8; ++j) {
        float2 v = base[j * NTHREADS];
        vx[j] = v.x; vy[j] = v.y;
        c[j] = fmaf(ex, vy[j], -fmaf(ey, vx[j], h));
    }
    int m = 0;
#pragma unroll
    for (int i = 0; i < 8; ++i) {
        bool valid = i < n;
        bool wrap = (i + 1 == n);
        const int ip1 = (i < 7) ? (i + 1) : 7;  // JAX OOB gather clamp
        float nx = wrap ? vx[0] : vx[ip1];
        float ny = wrap ? vy[0] : vy[ip1];
        float dc = c[i];
        float dn = wrap ? c[0] : c[ip1];
        float denom = dc - dn;
        float d = (fabsf(denom) < FEPS) ? 1.0f : denom;
        float t = dc * frcp(d);
        float ipx = fmaf(t, nx - vx[i], vx[i]);
        float ipy = fmaf(t, ny - vy[i], vy[i]);
        bool sc = dc >= 0.0f, sn = dn >= 0.0f;

        bool add_cur = valid && sc;
        int i1;
        if (i < 4) i1 = add_cur ? m : 8;                    // m <= 2i <= 6
        else       i1 = add_cur ? ((m < 7) ? m : 7) : 8;
        base[i1 * NTHREADS] = make_float2(vx[i], vy[i]);
        m += add_cur;

        bool add_ip = valid && (sc != sn);
        int i2;
        if (i < 4) i2 = add_ip ? m : 8;                     // m <= 2i+1 <= 7
        else       i2 = add_ip ? ((m < 7) ? m : 7) : 8;
        base[i2 * NTHREADS] = make_float2(ipx, ipy);
        m += add_ip;
    }
    return m;
}

// masked shoelace of the clipped polygon (reference wrap/clamp semantics)
__device__ __forceinline__ float shoelace(const float2* base, int n) {
    float vx[8], vy[8];
#pragma unroll
    for (int j = 0; j < 8; ++j) {
        float2 v = base[j * NTHREADS];
        vx[j] = v.x; vy[j] = v.y;
    }
    float acc = 0.0f;
#pragma unroll
    for (int i = 0; i < 8; ++i) {
        bool valid = i < n;
        bool wrap = (i + 1 == n);
        const int ip1 = (i < 7) ? (i + 1) : 7;
        float nx = wrap ? vx[0] : vx[ip1];
        float ny = wrap ? vy[0] : vy[ip1];
        float term = vx[i] * ny - vy[i] * nx;
        acc += valid ? term : 0.0f;
    }
    return acc;
}

__device__ __forceinline__ float finish(const Quad& q, float sl) {
    float inter = fabsf(0.5f * sl);
    float uni = q.area_p + q.area_t - inter;
    float iou = inter * frcp(uni + FEPS);
    return 1.0f - iou + q.d2c2;
}

__device__ __forceinline__ float diou_one(float2* base,
                                          float4 pa, float4 pb, float4 ta, float4 tb) {
    Quad q;
    setup(q, pa, pb, ta, tb);
    int n = clip1_to_lds(base, q);
    n = clip_pass<1>(base, n, q);
    n = clip_pass<2>(base, n, q);
    n = clip_pass<3>(base, n, q);
    return finish(q, shoelace(base, n));
}

// min-waves 4: VGPR budget 128 for the dual-quad working set (R7 showed the
// allocator picks its own count under looser bounds; the cap only guards
// against spill-inducing requests). LDS 37KB -> 4 blocks/CU = 16 waves/CU;
// DS latency is hidden by the in-thread A/B pass interleave, not TLP
// (R1: 92.6% VALUBusy at 33% occupancy).
__global__ __launch_bounds__(NTHREADS, 4) void diou_main(const float* __restrict__ pred,
                                                         const float* __restrict__ target,
                                                         double* __restrict__ partial,
                                                         int N) {
    // Per thread: 2 polygon buffers (quads A,B) x 9 slots (8 poly + 1 trash).
    // Slot stride = NTHREADS*8B = 2048B -> bank = 2*lane mod 32 for every
    // access: uniform 2-way (free), SQ_LDS_BANK_CONFLICT stays 0.
    __shared__ float2 poly[18 * NTHREADS];
    __shared__ double wsum[NTHREADS / 64];
    float2* baseA = &poly[threadIdx.x];
    float2* baseB = baseA + 9 * NTHREADS;

    const float4* p4 = reinterpret_cast<const float4*>(pred);
    const float4* t4 = reinterpret_cast<const float4*>(target);

    const int half = N >> 1;
    double acc = 0.0;
    // Two independent quads per thread (p, p+half), both load-coalesced.
    // Pass-granular source interleave: A's LDS write->read dependency for
    // pass k+1 has ~250 instrs of B's pass k in between -> DS latency hidden.
    for (int p = blockIdx.x * NTHREADS + threadIdx.x; p < half; p += NBLOCKS * NTHREADS) {
        const int iB = p + half;
        float4 paA = p4[2 * p], pbA = p4[2 * p + 1];
        float4 taA = t4[2 * p], tbA = t4[2 * p + 1];
        float4 paB = p4[2 * iB], pbB = p4[2 * iB + 1];
        float4 taB = t4[2 * iB], tbB = t4[2 * iB + 1];

        Quad A, B;
        setup(A, paA, pbA, taA, tbA);
        setup(B, paB, pbB, taB, tbB);
        int nA = clip1_to_lds(baseA, A);
        int nB = clip1_to_lds(baseB, B);
        nA = clip_pass<1>(baseA, nA, A);
        nB = clip_pass<1>(baseB, nB, B);
        nA = clip_pass<2>(baseA, nA, A);
        nB = clip_pass<2>(baseB, nB, B);
        nA = clip_pass<3>(baseA, nA, A);
        nB = clip_pass<3>(baseB, nB, B);
        float slA = shoelace(baseA, nA);
        float slB = shoelace(baseB, nB);
        acc += (double)finish(A, slA) + (double)finish(B, slB);
    }
    // odd-N remainder (not hit for N=2e6, kept for correctness)
    if ((N & 1) && blockIdx.x == 0 && threadIdx.x == 0) {
        const int last = N - 1;
        acc += (double)diou_one(baseA, p4[2 * last], p4[2 * last + 1],
                                t4[2 * last], t4[2 * last + 1]);
    }

    // wave shuffle reduction, then cross-wave via tiny LDS
#pragma unroll
    for (int off = 32; off > 0; off >>= 1) acc += __shfl_down(acc, off, 64);
    int lane = threadIdx.x & 63, wid = threadIdx.x >> 6;
    if (lane == 0) wsum[wid] = acc;
    __syncthreads();
    if (threadIdx.x == 0) {
        double s = 0.0;
#pragma unroll
        for (int w = 0; w < NTHREADS / 64; ++w) s += wsum[w];
        partial[blockIdx.x] = s;
    }
}

__global__ __launch_bounds__(256) void diou_finalize(const double* __restrict__ partial,
                                                     float* __restrict__ out,
                                                     int nparts, double invN) {
    __shared__ double s[256];
    double acc = 0.0;
    for (int i = threadIdx.x; i < nparts; i += 256) acc += partial[i];
    s[threadIdx.x] = acc;
    __syncthreads();
#pragma unroll
    for (int off = 128; off > 0; off >>= 1) {
        if (threadIdx.x < off) s[threadIdx.x] += s[threadIdx.x + off];
        __syncthreads();
    }
    if (threadIdx.x == 0) out[0] = (float)(s[0] * invN);
}

extern "C" void kernel_launch(void* const* d_in, const int* in_sizes, int n_in,
                              void* d_out, int out_size, void* d_ws, size_t ws_size,
                              hipStream_t stream) {
    const float* pred = (const float*)d_in[0];
    const float* target = (const float*)d_in[1];
    float* out = (float*)d_out;
    int N = in_sizes[0] / 8;

    double* partial = (double*)d_ws;  // NBLOCKS doubles = 16 KiB scratch

    diou_main<<<NBLOCKS, NTHREADS, 0, stream>>>(pred, target, partial, N);
    diou_finalize<<<1, 256, 0, stream>>>(partial, out, NBLOCKS, 1.0 / (double)N);
}

// Round 9
// 48.013 us; speedup vs baseline: 1.2337x; 1.2337x over previous
//
#include <hip/hip_runtime.h>

#define NBLOCKS 2048
#define NTHREADS 256
#define FEPS 1e-7f

__device__ __forceinline__ float frcp(float x) { return __builtin_amdgcn_rcpf(x); }

// ---------------------------------------------------------------------------
// Clip 1: input polygon is exactly the 4 oriented pred vertices (n==4) in
// registers; reference iterations 4..7 are provably no-ops. Appends scatter
// into LDS (slot = m, clamp elided since m<=7; slot 8 = trash when the append
// predicate is false). Ends by writing the SENTINEL: a copy of the first
// output vertex at slot min(m,8), so the next pass's wrap-read is static.
// c[j] = ex*vy[j] - ey*vx[j] - h, h = ex*Ay - ey*Ax (reference cross,
// re-associated; sign semantics preserved).
// ---------------------------------------------------------------------------
__device__ __forceinline__ int clip1_to_lds(float2* base,
                                            const float (&px)[4], const float (&py)[4],
                                            float ex, float ey, float h) {
    float c[4];
#pragma unroll
    for (int j = 0; j < 4; ++j)
        c[j] = fmaf(ex, py[j], -fmaf(ey, px[j], h));
    int m = 0;
#pragma unroll
    for (int i = 0; i < 4; ++i) {
        const int ip1 = (i + 1) & 3;  // mod(i+1, n=4)
        float dc = c[i], dn = c[ip1];
        float denom = dc - dn;
        float d = (fabsf(denom) < FEPS) ? 1.0f : denom;
        float t = dc * frcp(d);
        float ipx = fmaf(t, px[ip1] - px[i], px[i]);
        float ipy = fmaf(t, py[ip1] - py[i], py[i]);
        bool sc = dc >= 0.0f, sn = dn >= 0.0f;

        int i1 = sc ? m : 8;          // m <= 2i <= 6: no clamp
        base[i1 * NTHREADS] = make_float2(px[i], py[i]);
        m += sc;

        bool aip = (sc != sn);
        int i2 = aip ? m : 8;         // m <= 7: no clamp
        base[i2 * NTHREADS] = make_float2(ipx, ipy);
        m += aip;
    }
    // sentinel: first output vertex copied to slot min(m,8) (m<=8 here).
    // Same bits as slot 0 -> wrap-reads of the next pass are exact.
    float2 v0 = base[0];
    base[((m < 8) ? m : 8) * NTHREADS] = v0;
    return m;
}

// ---------------------------------------------------------------------------
// Clips 2..4: read all 9 slots (8 polygon + sentinel) to registers up front
// (static indices), scatter appends back. Reference semantics exact:
// valid = i<n; nxt = pts[mod(i+1, max(n,1))] -> via sentinel this is slot i+1
// for every case except i==7 with n>8, where JAX's OOB gather clamp makes the
// reference read pts[7] (3-op select at that one unrolled iteration).
// idx = min(m,7) elided where m<=2i proves it a no-op. Iterations where NO
// lane is valid are exact no-ops -> wave-uniform break (R3-proven win; R8
// showed removing it costs ~9us). Ends by writing the new sentinel.
// ---------------------------------------------------------------------------
__device__ __forceinline__ int clip_lds(float2* base, int n,
                                        float ex, float ey, float h) {
    float vx[9], vy[9], c[9];
#pragma unroll
    for (int j = 0; j < 9; ++j) {
        float2 v = base[j * NTHREADS];
        vx[j] = v.x; vy[j] = v.y;
        c[j] = fmaf(ex, vy[j], -fmaf(ey, vx[j], h));
    }
    int m = 0;
#pragma unroll
    for (int i = 0; i < 8; ++i) {
        if (i >= 4 && !__any(i < n)) break;
        bool valid = i < n;
        float nx, ny, dn;
        if (i == 7) {                 // JAX OOB clamp path: n>8 -> pts[7]
            bool big = n > 8;
            nx = big ? vx[7] : vx[8];
            ny = big ? vy[7] : vy[8];
            dn = big ? c[7] : c[8];
        } else {                      // sentinel makes the wrap static
            nx = vx[i + 1]; ny = vy[i + 1]; dn = c[i + 1];
        }
        float dc = c[i];
        float denom = dc - dn;
        float d = (fabsf(denom) < FEPS) ? 1.0f : denom;
        float t = dc * frcp(d);
        float ipx = fmaf(t, nx - vx[i], vx[i]);
        float ipy = fmaf(t, ny - vy[i], vy[i]);
        bool sc = dc >= 0.0f, sn = dn >= 0.0f;

        bool add_cur = valid && sc;
        int i1;
        if (i < 4) i1 = add_cur ? m : 8;                    // m <= 2i <= 6
        else       i1 = add_cur ? ((m < 7) ? m : 7) : 8;
        base[i1 * NTHREADS] = make_float2(vx[i], vy[i]);
        m += add_cur;

        bool add_ip = valid && (sc != sn);
        int i2;
        if (i < 4) i2 = add_ip ? m : 8;                     // m <= 2i+1 <= 7
        else       i2 = add_ip ? ((m < 7) ? m : 7) : 8;
        base[i2 * NTHREADS] = make_float2(ipx, ipy);
        m += add_ip;
    }
    // new sentinel for the next consumer (clip pass or shoelace)
    float2 v0 = base[0];
    base[((m < 8) ? m : 8) * NTHREADS] = v0;
    return m;
}

// masked shoelace of the clipped polygon (sentinel-based wrap, exact)
__device__ __forceinline__ float shoelace(const float2* base, int n) {
    float vx[9], vy[9];
#pragma unroll
    for (int j = 0; j < 9; ++j) {
        float2 v = base[j * NTHREADS];
        vx[j] = v.x; vy[j] = v.y;
    }
    float acc = 0.0f;
#pragma unroll
    for (int i = 0; i < 8; ++i) {
        if (i >= 4 && !__any(i < n)) break;
        bool valid = i < n;
        float nx, ny;
        if (i == 7) {
            bool big = n > 8;
            nx = big ? vx[7] : vx[8];
            ny = big ? vy[7] : vy[8];
        } else {
            nx = vx[i + 1]; ny = vy[i + 1];
        }
        float term = vx[i] * ny - vy[i] * nx;
        acc += valid ? term : 0.0f;
    }
    return acc;
}

__device__ __forceinline__ float diou_quad(float2* base,
                                           float4 pa, float4 pb, float4 ta, float4 tb) {
    float px[4] = {pa.x, pa.z, pb.x, pb.z};
    float py[4] = {pa.y, pa.w, pb.y, pb.w};
    float tx[4] = {ta.x, ta.z, tb.x, tb.z};
    float ty[4] = {ta.y, ta.w, tb.y, tb.w};

    float sa_p = 0.5f * ((px[0] * py[1] - py[0] * px[1]) +
                         (px[1] * py[2] - py[1] * px[2]) +
                         (px[2] * py[3] - py[2] * px[3]) +
                         (px[3] * py[0] - py[3] * px[0]));
    float sa_t = 0.5f * ((tx[0] * ty[1] - ty[0] * tx[1]) +
                         (tx[1] * ty[2] - ty[1] * tx[2]) +
                         (tx[2] * ty[3] - ty[2] * tx[3]) +
                         (tx[3] * ty[0] - ty[3] * tx[0]));

    if (sa_p < 0.0f) {  // reverse -> CCW (centers/minmax invariant to order)
        float t0;
        t0 = px[0]; px[0] = px[3]; px[3] = t0;
        t0 = px[1]; px[1] = px[2]; px[2] = t0;
        t0 = py[0]; py[0] = py[3]; py[3] = t0;
        t0 = py[1]; py[1] = py[2]; py[2] = t0;
    }
    if (sa_t < 0.0f) {
        float t0;
        t0 = tx[0]; tx[0] = tx[3]; tx[3] = t0;
        t0 = tx[1]; tx[1] = tx[2]; tx[2] = t0;
        t0 = ty[0]; ty[0] = ty[3]; ty[3] = t0;
        t0 = ty[1]; ty[1] = ty[2]; ty[2] = t0;
    }
    float area_p = fabsf(sa_p);
    float area_t = fabsf(sa_t);

    int n;
    {
        float ex = tx[1] - tx[0], ey = ty[1] - ty[0];
        n = clip1_to_lds(base, px, py, ex, ey, fmaf(ex, ty[0], -ey * tx[0]));
    }
    {
        float ex = tx[2] - tx[1], ey = ty[2] - ty[1];
        n = clip_lds(base, n, ex, ey, fmaf(ex, ty[1], -ey * tx[1]));
    }
    {
        float ex = tx[3] - tx[2], ey = ty[3] - ty[2];
        n = clip_lds(base, n, ex, ey, fmaf(ex, ty[2], -ey * tx[2]));
    }
    {
        float ex = tx[0] - tx[3], ey = ty[0] - ty[3];
        n = clip_lds(base, n, ex, ey, fmaf(ex, ty[3], -ey * tx[3]));
    }

    float inter = fabsf(0.5f * shoelace(base, n));
    float uni = area_p + area_t - inter;
    float iou = inter * frcp(uni + FEPS);

    float cpx = 0.25f * (px[0] + px[1] + px[2] + px[3]);
    float cpy = 0.25f * (py[0] + py[1] + py[2] + py[3]);
    float ctx = 0.25f * (tx[0] + tx[1] + tx[2] + tx[3]);
    float cty = 0.25f * (ty[0] + ty[1] + ty[2] + ty[3]);
    float d2 = (cpx - ctx) * (cpx - ctx) + (cpy - cty) * (cpy - cty);

    float minx = fminf(fminf(fminf(px[0], px[1]), fminf(px[2], px[3])),
                       fminf(fminf(tx[0], tx[1]), fminf(tx[2], tx[3])));
    float maxx = fmaxf(fmaxf(fmaxf(px[0], px[1]), fmaxf(px[2], px[3])),
                       fmaxf(fmaxf(tx[0], tx[1]), fmaxf(tx[2], tx[3])));
    float miny = fminf(fminf(fminf(py[0], py[1]), fminf(py[2], py[3])),
                       fminf(fminf(ty[0], ty[1]), fminf(ty[2], ty[3])));
    float maxy = fmaxf(fmaxf(fmaxf(py[0], py[1]), fmaxf(py[2], py[3])),
                       fmaxf(fmaxf(ty[0], ty[1]), fmaxf(ty[2], ty[3])));
    float c2 = (maxx - minx) * (maxx - minx) + (maxy - miny) * (maxy - miny) + FEPS;

    return 1.0f - iou + d2 * frcp(c2);
}

// (256,4): VGPR budget 128 — guards only against spill-inducing requests
// (R4: min-waves 8 -> 32 VGPR -> 100MB spill traffic). Allocator settles
// ~36-56 on its own (R7). LDS 18.4KB -> 8 blocks/CU; TLP (32 waves/CU) is
// the latency-hiding mechanism (R8: trading LDS for in-thread ILP lost 9us).
__global__ __launch_bounds__(NTHREADS, 4) void diou_main(const float* __restrict__ pred,
                                                         const float* __restrict__ target,
                                                         double* __restrict__ partial,
                                                         int N) {
    // 9 slots/thread: 8 polygon + slot 8 = trash/sentinel-overflow.
    // Slot stride = NTHREADS*8B = 2048B -> bank = 2*lane mod 32 for every
    // access: uniform 2-way (free) -> SQ_LDS_BANK_CONFLICT stays 0.
    __shared__ float2 poly[9 * NTHREADS];
    __shared__ double wsum[NTHREADS / 64];
    float2* base = &poly[threadIdx.x];

    const float4* p4 = reinterpret_cast<const float4*>(pred);
    const float4* t4 = reinterpret_cast<const float4*>(target);

    // Simple grid-stride loop (R3-proven): TLP hides load latency; explicit
    // SW pipelining regressed (R4/R5), dual-quad ILP regressed (R8).
    double acc = 0.0;
    for (int i = blockIdx.x * NTHREADS + threadIdx.x; i < N; i += NBLOCKS * NTHREADS) {
        float4 pa = p4[2 * i], pb = p4[2 * i + 1];
        float4 ta = t4[2 * i], tb = t4[2 * i + 1];
        acc += (double)diou_quad(base, pa, pb, ta, tb);
    }

    // wave shuffle reduction, then cross-wave via tiny LDS
#pragma unroll
    for (int off = 32; off > 0; off >>= 1) acc += __shfl_down(acc, off, 64);
    int lane = threadIdx.x & 63, wid = threadIdx.x >> 6;
    if (lane == 0) wsum[wid] = acc;
    __syncthreads();
    if (threadIdx.x == 0) {
        double s = 0.0;
#pragma unroll
        for (int w = 0; w < NTHREADS / 64; ++w) s += wsum[w];
        partial[blockIdx.x] = s;
    }
}

__global__ __launch_bounds__(256) void diou_finalize(const double* __restrict__ partial,
                                                     float* __restrict__ out,
                                                     int nparts, double invN) {
    __shared__ double s[256];
    double acc = 0.0;
    for (int i = threadIdx.x; i < nparts; i += 256) acc += partial[i];
    s[threadIdx.x] = acc;
    __syncthreads();
#pragma unroll
    for (int off = 128; off > 0; off >>= 1) {
        if (threadIdx.x < off) s[threadIdx.x] += s[threadIdx.x + off];
        __syncthreads();
    }
    if (threadIdx.x == 0) out[0] = (float)(s[0] * invN);
}

extern "C" void kernel_launch(void* const* d_in, const int* in_sizes, int n_in,
                              void* d_out, int out_size, void* d_ws, size_t ws_size,
                              hipStream_t stream) {
    const float* pred = (const float*)d_in[0];
    const float* target = (const float*)d_in[1];
    float* out = (float*)d_out;
    int N = in_sizes[0] / 8;

    double* partial = (double*)d_ws;  // NBLOCKS doubles = 16 KiB scratch

    diou_main<<<NBLOCKS, NTHREADS, 0, stream>>>(pred, target, partial, N);
    diou_finalize<<<1, 256, 0, stream>>>(partial, out, NBLOCKS, 1.0 / (double)N);
}

// Round 10
// 47.158 us; speedup vs baseline: 1.2561x; 1.0181x over previous
//
#include <hip/hip_runtime.h>

#define NBLOCKS 2048
#define NTHREADS 256
#define FEPS 1e-7f

__device__ __forceinline__ float frcp(float x) { return __builtin_amdgcn_rcpf(x); }
// nested triples -> v_min3_f32 / v_max3_f32 (R8-validated, absmax 0.0)
__device__ __forceinline__ float fmin3(float a, float b, float c) { return fminf(fminf(a, b), c); }
__device__ __forceinline__ float fmax3(float a, float b, float c) { return fmaxf(fmaxf(a, b), c); }

// ---------------------------------------------------------------------------
// Clip 1: input polygon is exactly the 4 oriented pred vertices (n==4) in
// registers; reference iterations 4..7 are provably no-ops. Appends scatter
// into LDS (slot = m, clamp elided since m<=7; slot 8 = trash when the append
// predicate is false). Output count m <= 6 (appends = #kept + #sign-changes
// <= k + 2*min(k,4-k), maximized at 6) -> sentinel slot = m, no clamp.
// c[j] = ex*vy[j] - ey*vx[j] - h, h = ex*Ay - ey*Ax (reference cross,
// re-associated; sign semantics preserved).
// ---------------------------------------------------------------------------
__device__ __forceinline__ int clip1_to_lds(float2* base,
                                            const float (&px)[4], const float (&py)[4],
                                            float ex, float ey, float h) {
    float c[4];
#pragma unroll
    for (int j = 0; j < 4; ++j)
        c[j] = fmaf(ex, py[j], -fmaf(ey, px[j], h));
    int m = 0;
#pragma unroll
    for (int i = 0; i < 4; ++i) {
        const int ip1 = (i + 1) & 3;  // mod(i+1, n=4)
        float dc = c[i], dn = c[ip1];
        float denom = dc - dn;
        float d = (fabsf(denom) < FEPS) ? 1.0f : denom;
        float t = dc * frcp(d);
        float ipx = fmaf(t, px[ip1] - px[i], px[i]);
        float ipy = fmaf(t, py[ip1] - py[i], py[i]);
        bool sc = dc >= 0.0f, sn = dn >= 0.0f;

        int i1 = sc ? m : 8;          // m <= 2i <= 6: no clamp
        base[i1 * NTHREADS] = make_float2(px[i], py[i]);
        m += sc;

        bool aip = (sc != sn);
        int i2 = aip ? m : 8;         // m <= 7: no clamp
        base[i2 * NTHREADS] = make_float2(ipx, ipy);
        m += aip;
    }
    // sentinel: copy of first output vertex at slot m (m <= 6, no clamp).
    // Same bits as slot 0 -> pass-2 wrap-reads are static and exact.
    float2 v0 = base[0];
    base[m * NTHREADS] = v0;
    return m;
}

// ---------------------------------------------------------------------------
// Clip pass 2 SPECIALIZED: input n <= 6 (proved above), so reference
// iterations 6..7 are no-ops for ALL lanes -> statically truncated to 6, and
// only slots 0..6 (max polygon 0..5 + sentinel at m<=6) are live -> 7 reads.
// Reference semantics otherwise exact: valid = i<n; sentinel makes the wrap
// read static; idx = min(m,7) elided where m<=2i proves it a no-op.
// Output m <= 9 -> sentinel at min(m,8).
// ---------------------------------------------------------------------------
__device__ __forceinline__ int clip_pass2(float2* base, int n,
                                          float ex, float ey, float h) {
    float vx[7], vy[7], c[7];
#pragma unroll
    for (int j = 0; j < 7; ++j) {
        float2 v = base[j * NTHREADS];
        vx[j] = v.x; vy[j] = v.y;
        c[j] = fmaf(ex, vy[j], -fmaf(ey, vx[j], h));
    }
    int m = 0;
#pragma unroll
    for (int i = 0; i < 6; ++i) {
        if (i >= 4 && !__any(i < n)) break;
        bool valid = i < n;
        float nx = vx[i + 1], ny = vy[i + 1], dn = c[i + 1];  // sentinel wrap
        float dc = c[i];
        float denom = dc - dn;
        float d = (fabsf(denom) < FEPS) ? 1.0f : denom;
        float t = dc * frcp(d);
        float ipx = fmaf(t, nx - vx[i], vx[i]);
        float ipy = fmaf(t, ny - vy[i], vy[i]);
        bool sc = dc >= 0.0f, sn = dn >= 0.0f;

        bool add_cur = valid && sc;
        int i1;
        if (i < 4) i1 = add_cur ? m : 8;                    // m <= 2i <= 6
        else       i1 = add_cur ? ((m < 7) ? m : 7) : 8;
        base[i1 * NTHREADS] = make_float2(vx[i], vy[i]);
        m += add_cur;

        bool add_ip = valid && (sc != sn);
        int i2;
        if (i < 4) i2 = add_ip ? m : 8;                     // m <= 2i+1 <= 7
        else       i2 = add_ip ? ((m < 7) ? m : 7) : 8;
        base[i2 * NTHREADS] = make_float2(ipx, ipy);
        m += add_ip;
    }
    float2 v0 = base[0];
    base[((m < 8) ? m : 8) * NTHREADS] = v0;
    return m;
}

// ---------------------------------------------------------------------------
// Clips 3..4: full 8 iterations, 9 slot-reads (n can reach 9+ upstream via
// the min(m,7) clobber path). valid = i<n; sentinel wrap; at i==7 with n>8
// JAX's OOB gather clamp makes the reference read pts[7] (3-op select).
// Iterations where NO lane is valid are exact no-ops -> wave-uniform break
// (R3-proven; R8 showed removing it costs ~9us). Ends writing new sentinel.
// ---------------------------------------------------------------------------
__device__ __forceinline__ int clip_lds(float2* base, int n,
                                        float ex, float ey, float h) {
    float vx[9], vy[9], c[9];
#pragma unroll
    for (int j = 0; j < 9; ++j) {
        float2 v = base[j * NTHREADS];
        vx[j] = v.x; vy[j] = v.y;
        c[j] = fmaf(ex, vy[j], -fmaf(ey, vx[j], h));
    }
    int m = 0;
#pragma unroll
    for (int i = 0; i < 8; ++i) {
        if (i >= 4 && !__any(i < n)) break;
        bool valid = i < n;
        float nx, ny, dn;
        if (i == 7) {                 // JAX OOB clamp path: n>8 -> pts[7]
            bool big = n > 8;
            nx = big ? vx[7] : vx[8];
            ny = big ? vy[7] : vy[8];
            dn = big ? c[7] : c[8];
        } else {                      // sentinel makes the wrap static
            nx = vx[i + 1]; ny = vy[i + 1]; dn = c[i + 1];
        }
        float dc = c[i];
        float denom = dc - dn;
        float d = (fabsf(denom) < FEPS) ? 1.0f : denom;
        float t = dc * frcp(d);
        float ipx = fmaf(t, nx - vx[i], vx[i]);
        float ipy = fmaf(t, ny - vy[i], vy[i]);
        bool sc = dc >= 0.0f, sn = dn >= 0.0f;

        bool add_cur = valid && sc;
        int i1;
        if (i < 4) i1 = add_cur ? m : 8;                    // m <= 2i <= 6
        else       i1 = add_cur ? ((m < 7) ? m : 7) : 8;
        base[i1 * NTHREADS] = make_float2(vx[i], vy[i]);
        m += add_cur;

        bool add_ip = valid && (sc != sn);
        int i2;
        if (i < 4) i2 = add_ip ? m : 8;                     // m <= 2i+1 <= 7
        else       i2 = add_ip ? ((m < 7) ? m : 7) : 8;
        base[i2 * NTHREADS] = make_float2(ipx, ipy);
        m += add_ip;
    }
    float2 v0 = base[0];
    base[((m < 8) ? m : 8) * NTHREADS] = v0;
    return m;
}

// masked shoelace of the clipped polygon (sentinel-based wrap, exact)
__device__ __forceinline__ float shoelace(const float2* base, int n) {
    float vx[9], vy[9];
#pragma unroll
    for (int j = 0; j < 9; ++j) {
        float2 v = base[j * NTHREADS];
        vx[j] = v.x; vy[j] = v.y;
    }
    float acc = 0.0f;
#pragma unroll
    for (int i = 0; i < 8; ++i) {
        if (i >= 4 && !__any(i < n)) break;
        bool valid = i < n;
        float nx, ny;
        if (i == 7) {
            bool big = n > 8;
            nx = big ? vx[7] : vx[8];
            ny = big ? vy[7] : vy[8];
        } else {
            nx = vx[i + 1]; ny = vy[i + 1];
        }
        float term = vx[i] * ny - vy[i] * nx;
        acc += valid ? term : 0.0f;
    }
    return acc;
}

__device__ __forceinline__ float diou_quad(float2* base,
                                           float4 pa, float4 pb, float4 ta, float4 tb) {
    float px[4] = {pa.x, pa.z, pb.x, pb.z};
    float py[4] = {pa.y, pa.w, pb.y, pb.w};
    float tx[4] = {ta.x, ta.z, tb.x, tb.z};
    float ty[4] = {ta.y, ta.w, tb.y, tb.w};

    // quad shoelace via determinant identity (R8-validated, absmax 0.0):
    // 2A = (x0-x2)(y1-y3) - (x1-x3)(y0-y2)
    float sa_p = 0.5f * ((px[0] - px[2]) * (py[1] - py[3]) -
                         (px[1] - px[3]) * (py[0] - py[2]));
    float sa_t = 0.5f * ((tx[0] - tx[2]) * (ty[1] - ty[3]) -
                         (tx[1] - tx[3]) * (ty[0] - ty[2]));

    if (sa_p < 0.0f) {  // reverse -> CCW (centers/minmax invariant to order)
        float t0;
        t0 = px[0]; px[0] = px[3]; px[3] = t0;
        t0 = px[1]; px[1] = px[2]; px[2] = t0;
        t0 = py[0]; py[0] = py[3]; py[3] = t0;
        t0 = py[1]; py[1] = py[2]; py[2] = t0;
    }
    if (sa_t < 0.0f) {
        float t0;
        t0 = tx[0]; tx[0] = tx[3]; tx[3] = t0;
        t0 = tx[1]; tx[1] = tx[2]; tx[2] = t0;
        t0 = ty[0]; ty[0] = ty[3]; ty[3] = t0;
        t0 = ty[1]; ty[1] = ty[2]; ty[2] = t0;
    }
    float area_p = fabsf(sa_p);
    float area_t = fabsf(sa_t);

    int n;
    {
        float ex = tx[1] - tx[0], ey = ty[1] - ty[0];
        n = clip1_to_lds(base, px, py, ex, ey, fmaf(ex, ty[0], -ey * tx[0]));
    }
    {
        float ex = tx[2] - tx[1], ey = ty[2] - ty[1];
        n = clip_pass2(base, n, ex, ey, fmaf(ex, ty[1], -ey * tx[1]));
    }
    {
        float ex = tx[3] - tx[2], ey = ty[3] - ty[2];
        n = clip_lds(base, n, ex, ey, fmaf(ex, ty[2], -ey * tx[2]));
    }
    {
        float ex = tx[0] - tx[3], ey = ty[0] - ty[3];
        n = clip_lds(base, n, ex, ey, fmaf(ex, ty[3], -ey * tx[3]));
    }

    float inter = fabsf(0.5f * shoelace(base, n));
    float uni = area_p + area_t - inter;
    float iou = inter * frcp(uni + FEPS);

    float cpx = 0.25f * (px[0] + px[1] + px[2] + px[3]);
    float cpy = 0.25f * (py[0] + py[1] + py[2] + py[3]);
    float ctx = 0.25f * (tx[0] + tx[1] + tx[2] + tx[3]);
    float cty = 0.25f * (ty[0] + ty[1] + ty[2] + ty[3]);
    float d2 = (cpx - ctx) * (cpx - ctx) + (cpy - cty) * (cpy - cty);

    float minx = fmin3(fmin3(px[0], px[1], px[2]),
                       fmin3(px[3], tx[0], tx[1]),
                       fminf(tx[2], tx[3]));
    float maxx = fmax3(fmax3(px[0], px[1], px[2]),
                       fmax3(px[3], tx[0], tx[1]),
                       fmaxf(tx[2], tx[3]));
    float miny = fmin3(fmin3(py[0], py[1], py[2]),
                       fmin3(py[3], ty[0], ty[1]),
                       fminf(ty[2], ty[3]));
    float maxy = fmax3(fmax3(py[0], py[1], py[2]),
                       fmax3(py[3], ty[0], ty[1]),
                       fmaxf(ty[2], ty[3]));
    float bx = maxx - minx, by = maxy - miny;
    float c2 = bx * bx + by * by + FEPS;

    return 1.0f - iou + d2 * frcp(c2);
}

// (256,4): VGPR budget 128 — guards only against spill-inducing requests
// (R4: min-waves 8 -> 32 VGPR -> 100MB spill traffic). Allocator settles
// ~32-52 on its own (R7/R9). LDS 18.4KB -> 8 blocks/CU; TLP (32 waves/CU) is
// the latency-hiding mechanism (R8: trading LDS for in-thread ILP lost 9us).
__global__ __launch_bounds__(NTHREADS, 4) void diou_main(const float* __restrict__ pred,
                                                         const float* __restrict__ target,
                                                         double* __restrict__ partial,
                                                         int N) {
    // 9 slots/thread: 8 polygon + slot 8 = trash/sentinel-overflow.
    // Slot stride = NTHREADS*8B = 2048B -> bank = 2*lane mod 32 for every
    // access: uniform 2-way (free) -> SQ_LDS_BANK_CONFLICT stays 0.
    __shared__ float2 poly[9 * NTHREADS];
    __shared__ double wsum[NTHREADS / 64];
    float2* base = &poly[threadIdx.x];

    const float4* p4 = reinterpret_cast<const float4*>(pred);
    const float4* t4 = reinterpret_cast<const float4*>(target);

    // Simple grid-stride loop (R3-proven): TLP hides load latency; explicit
    // SW pipelining regressed (R4/R5), dual-quad ILP regressed (R8).
    double acc = 0.0;
    for (int i = blockIdx.x * NTHREADS + threadIdx.x; i < N; i += NBLOCKS * NTHREADS) {
        float4 pa = p4[2 * i], pb = p4[2 * i + 1];
        float4 ta = t4[2 * i], tb = t4[2 * i + 1];
        acc += (double)diou_quad(base, pa, pb, ta, tb);
    }

    // wave shuffle reduction, then cross-wave via tiny LDS
#pragma unroll
    for (int off = 32; off > 0; off >>= 1) acc += __shfl_down(acc, off, 64);
    int lane = threadIdx.x & 63, wid = threadIdx.x >> 6;
    if (lane == 0) wsum[wid] = acc;
    __syncthreads();
    if (threadIdx.x == 0) {
        double s = 0.0;
#pragma unroll
        for (int w = 0; w < NTHREADS / 64; ++w) s += wsum[w];
        partial[blockIdx.x] = s;
    }
}

__global__ __launch_bounds__(256) void diou_finalize(const double* __restrict__ partial,
                                                     float* __restrict__ out,
                                                     int nparts, double invN) {
    __shared__ double s[256];
    double acc = 0.0;
    for (int i = threadIdx.x; i < nparts; i += 256) acc += partial[i];
    s[threadIdx.x] = acc;
    __syncthreads();
#pragma unroll
    for (int off = 128; off > 0; off >>= 1) {
        if (threadIdx.x < off) s[threadIdx.x] += s[threadIdx.x + off];
        __syncthreads();
    }
    if (threadIdx.x == 0) out[0] = (float)(s[0] * invN);
}

extern "C" void kernel_launch(void* const* d_in, const int* in_sizes, int n_in,
                              void* d_out, int out_size, void* d_ws, size_t ws_size,
                              hipStream_t stream) {
    const float* pred = (const float*)d_in[0];
    const float* target = (const float*)d_in[1];
    float* out = (float*)d_out;
    int N = in_sizes[0] / 8;

    double* partial = (double*)d_ws;  // NBLOCKS doubles = 16 KiB scratch

    diou_main<<<NBLOCKS, NTHREADS, 0, stream>>>(pred, target, partial, N);
    diou_finalize<<<1, 256, 0, stream>>>(partial, out, NBLOCKS, 1.0 / (double)N);
}